// Round 10
// baseline (137.983 us; speedup 1.0000x reference)
//
#include <hip/hip_runtime.h>
#include <hip/hip_bf16.h>
#include <cstdint>

#define NV 64
#define NH 128
#define NB 16384
#define NCHUNK 37       // 8 diag + 28 off-diag (I<J) + 1 order-1; 64 k each
#define PSLICE (NB * NH)  // floats per ks partial slice (8 MB)

typedef __bf16 bf16x8_t __attribute__((ext_vector_type(8)));
typedef float f32x16_t __attribute__((ext_vector_type(16)));
typedef float f32x2_t __attribute__((ext_vector_type(2)));
typedef uint32_t u32x4_t __attribute__((ext_vector_type(4)));
typedef uint32_t u32x2_t __attribute__((ext_vector_type(2)));

__device__ __forceinline__ uint32_t bf16_rne(float f) {
  uint32_t u = __float_as_uint(f);
  return (u + 0x7fffu + ((u >> 16) & 1u)) >> 16;
}

// ---------------------------------------------------------------------------
// Pre-pass (validated r8/r9): bf16 B' frags in mfma_32x32x16 B-layout,
// symmetrized triangle. Frag fi = (c*4+kk)*4 + fh2 (1 KB): lane l holds
// B'[h = fh2*32 + (l&31)][slot = kk*16 + (l>>5)*8 + t].
// ---------------------------------------------------------------------------
__global__ void cvt_kernel(const float* __restrict__ w1f,
                           const float* __restrict__ w2f,
                           uint8_t* __restrict__ frag) {
  __shared__ float W[4096];
  __shared__ float w1c[64];
  const int tid = threadIdx.x;
  const int h = blockIdx.x;
  {
    const float* src = w2f + (size_t)h * 4096;
#pragma unroll
    for (int u = 0; u < 4; ++u)
      *(float4*)(&W[u * 1024 + tid * 4]) =
          *(const float4*)(src + u * 1024 + tid * 4);
  }
  if (tid < 64) w1c[tid] = w1f[tid * 128 + h];
  __syncthreads();
  const int fh2 = h >> 5, hl = h & 31;
  for (int idx = tid; idx < 296; idx += 256) {  // idx = c*8 + kk*2 + lh
    int c = idx >> 3, kk = (idx >> 1) & 3, lh = idx & 1;
    int a = kk * 2 + lh;
    float v[8];
    if (c < 8) {
      int ib = (c * 8 + a) * 64 + c * 8;
#pragma unroll
      for (int t = 0; t < 8; ++t) v[t] = 0.5f * W[ib + t];
    } else if (c < 36) {
      int o = c - 8, I = 0;
      while (o >= 7 - I) { o -= 7 - I; ++I; }
      int J = I + 1 + o;
      int i = I * 8 + a;
#pragma unroll
      for (int t = 0; t < 8; ++t) {
        int j = J * 8 + t;
        v[t] = 0.5f * (W[i * 64 + j] + W[j * 64 + i]);
      }
    } else {
      int sb = kk * 16 + lh * 8;
#pragma unroll
      for (int t = 0; t < 8; ++t) v[t] = w1c[sb + t];
    }
    uint4 o4;
    o4.x = (bf16_rne(v[1]) << 16) | bf16_rne(v[0]);
    o4.y = (bf16_rne(v[3]) << 16) | bf16_rne(v[2]);
    o4.z = (bf16_rne(v[5]) << 16) | bf16_rne(v[4]);
    o4.w = (bf16_rne(v[7]) << 16) | bf16_rne(v[6]);
    *(uint4*)(frag + ((size_t)((c * 4 + kk) * 4 + fh2) << 10) +
              ((lh * 32 + hl) << 4)) = o4;
  }
}

// ---------------------------------------------------------------------------
// Main: P[ks][m][h] = partial over this ks's chunks of A[m,k]B'[h,k].
// Wave = 64m x 32h: 2 im-tiles (mfma_f32_32x32x16_bf16) share each B-frag.
// Lane owns TWO x rows as bf16-PACKED u32 (32 regs/row): expensive to remat
// (2 loads + RNE math per reg) -> stays resident (r9 lesson). Block = 256 thr
// (4 hq waves); grid (256 m-tiles, 3 ks) = 12 waves/CU latency hiding.
// ---------------------------------------------------------------------------
__device__ __forceinline__ uint32_t pack2(f32x2_t pr) {
  u32x2_t u = __builtin_bit_cast(u32x2_t, pr);
  return __builtin_amdgcn_perm(u[1], u[0], 0x07060302);  // hi halves (trunc)
}

template <int C0, int C1>
__device__ __forceinline__ void kloop(const uint8_t* pw,
                                      const uint32_t xpk[2][32], int lh,
                                      f32x16_t acc[2]) {
  constexpr int CI[36] = {0,1,2,3,4,5,6,7, 0,0,0,0,0,0,0, 1,1,1,1,1,1,
                          2,2,2,2,2, 3,3,3,3, 4,4,4, 5,5, 6};
  constexpr int CJ[36] = {0,1,2,3,4,5,6,7, 1,2,3,4,5,6,7, 2,3,4,5,6,7,
                          3,4,5,6,7, 4,5,6,7, 5,6,7, 6,7, 7};
#pragma unroll
  for (int c = C0; c < C1; ++c) {
    bf16x8_t bc[4];
#pragma unroll
    for (int kk = 0; kk < 4; ++kk)
      bc[kk] = *(const bf16x8_t*)(pw + (size_t)c * 16384 + kk * 4096);
    const int I = CI[c], J = CJ[c];
#pragma unroll
    for (int kk = 0; kk < 4; ++kk) {
#pragma unroll
      for (int im = 0; im < 2; ++im) {
        uint32_t su = xpk[im][I * 4 + kk];
        uint32_t sb = lh ? (su & 0xffff0000u) : (su << 16);
        float s = __uint_as_float(sb);
        f32x2_t s2 = {s, s};
        u32x4_t adv;
#pragma unroll
        for (int tt = 0; tt < 4; ++tt) {
          uint32_t xu = xpk[im][J * 4 + tt];
          f32x2_t xv = {__uint_as_float(xu << 16),
                        __uint_as_float(xu & 0xffff0000u)};
          adv[tt] = pack2(s2 * xv);  // v_pk_mul_f32 + v_perm
        }
        acc[im] = __builtin_amdgcn_mfma_f32_32x32x16_bf16(
            __builtin_bit_cast(bf16x8_t, adv), bc[kk], acc[im], 0, 0, 0);
      }
    }
  }
}

__launch_bounds__(256, 3)
__global__ void rbm_main(const float* __restrict__ xg,
                         const uint8_t* __restrict__ frag,
                         float* __restrict__ P) {
  const int tid = threadIdx.x;
  const int hq = tid >> 6;      // wave = h quarter
  const int lane = tid & 63;
  const int l31 = lane & 31;
  const int lh = lane >> 5;
  const int mblk = blockIdx.x * 64;
  const int ks = blockIdx.y;

  // two x rows -> bf16-packed registers (32 u32 per row)
  uint32_t xpk[2][32];
#pragma unroll
  for (int im = 0; im < 2; ++im) {
    const float* p = xg + (size_t)(mblk + im * 32 + l31) * NV;
#pragma unroll
    for (int g = 0; g < 16; ++g) {
      float4 v = *(const float4*)(p + g * 4);
      xpk[im][g * 2]     = (bf16_rne(v.y) << 16) | bf16_rne(v.x);
      xpk[im][g * 2 + 1] = (bf16_rne(v.w) << 16) | bf16_rne(v.z);
    }
  }

  const uint8_t* pw = frag + hq * 1024 + (size_t)lane * 16;
  f32x16_t acc[2] = {(f32x16_t)0.0f, (f32x16_t)0.0f};

  if (ks == 0) {
    kloop<0, 12>(pw, xpk, lh, acc);
  } else if (ks == 1) {
    kloop<12, 24>(pw, xpk, lh, acc);
  } else {
    kloop<24, 36>(pw, xpk, lh, acc);
    // tail chunk 36 (order-1): A = x directly — xpk IS the bf16 A-frag
#pragma unroll
    for (int kk = 0; kk < 4; ++kk) {
      bf16x8_t bt = *(const bf16x8_t*)(pw + (size_t)36 * 16384 + kk * 4096);
#pragma unroll
      for (int im = 0; im < 2; ++im) {
        u32x4_t adv;
#pragma unroll
        for (int tt = 0; tt < 4; ++tt)
          adv[tt] = xpk[im][kk * 8 + lh * 4 + tt];
        acc[im] = __builtin_amdgcn_mfma_f32_32x32x16_bf16(
            __builtin_bit_cast(bf16x8_t, adv), bt, acc[im], 0, 0, 0);
      }
    }
  }

  // store partials. C/D layout (r8-validated): col h = hq*32 + l31,
  // row m (within tile) = (r&3) + 8*(r>>2) + 4*lh.
  float* pp = P + (size_t)ks * PSLICE + (size_t)mblk * NH + hq * 32 + l31;
#pragma unroll
  for (int im = 0; im < 2; ++im)
#pragma unroll
    for (int r = 0; r < 16; ++r) {
      int mloc = im * 32 + (r & 3) + 8 * (r >> 2) + 4 * lh;
      pp[(size_t)mloc * NH] = acc[im][r];
    }
}

// ---------------------------------------------------------------------------
// Reduce: psi[m] = prod_h cos(P0+P1+P2+bias). Wave: 8 m sequential; lane
// owns h pair (2l, 2l+1); width-64 product butterfly.
// ---------------------------------------------------------------------------
__global__ void reduce_kernel(const float* __restrict__ P,
                              const float* __restrict__ biasg,
                              float* __restrict__ outg) {
  const int tid = threadIdx.x;
  const int wv = tid >> 6;
  const int lane = tid & 63;
  const int m0 = blockIdx.x * 32 + wv * 8;
  const float2 b2 = *(const float2*)(biasg + 2 * lane);
  const float INV2PI = 0.15915494309189535f;
#pragma unroll
  for (int u = 0; u < 8; ++u) {
    const int m = m0 + u;
    const float* pm = P + (size_t)m * NH + 2 * lane;
    float2 a0 = *(const float2*)(pm);
    float2 a1 = *(const float2*)(pm + PSLICE);
    float2 a2 = *(const float2*)(pm + 2 * (size_t)PSLICE);
    float ax = a0.x + a1.x + a2.x + b2.x;
    float ay = a0.y + a1.y + a2.y + b2.y;
    float pr = __builtin_amdgcn_cosf(ax * INV2PI) *
               __builtin_amdgcn_cosf(ay * INV2PI);
#pragma unroll
    for (int ofs = 1; ofs < 64; ofs <<= 1)
      pr *= __shfl_xor(pr, ofs, 64);
    if (lane == 0) outg[m] = pr;
  }
}

extern "C" void kernel_launch(void* const* d_in, const int* in_sizes, int n_in,
                              void* d_out, int out_size, void* d_ws, size_t ws_size,
                              hipStream_t stream) {
  const float* x   = (const float*)d_in[0];
  const float* w1f = (const float*)d_in[1];
  const float* w2f = (const float*)d_in[2];
  const float* hb  = (const float*)d_in[3];
  float* out = (float*)d_out;
  uint8_t* frag = (uint8_t*)d_ws;                    // 592 KB bf16 frags
  float* P = (float*)((uint8_t*)d_ws + (1 << 20));   // 3 x 8 MB partials
  (void)in_sizes; (void)n_in; (void)out_size; (void)ws_size;

  cvt_kernel<<<128, 256, 0, stream>>>(w1f, w2f, frag);
  rbm_main<<<dim3(NB / 64, 3), 256, 0, stream>>>(x, frag, P);
  reduce_kernel<<<NB / 32, 256, 0, stream>>>(P, hb, out);
}

// Round 11
// 106.062 us; speedup vs baseline: 1.3010x; 1.3010x over previous
//
#include <hip/hip_runtime.h>
#include <hip/hip_bf16.h>
#include <cstdint>

#define NV 64
#define NH 128
#define NB 16384
#define NCHUNK 37   // 8 diag + 28 off-diag (I<J) + 1 order-1; 64 k each

typedef __bf16 bf16x8_t __attribute__((ext_vector_type(8)));
typedef float f32x16_t __attribute__((ext_vector_type(16)));
typedef float f32x2_t __attribute__((ext_vector_type(2)));
typedef uint32_t u32x4_t __attribute__((ext_vector_type(4)));
typedef uint32_t u32x2_t __attribute__((ext_vector_type(2)));

__device__ __forceinline__ uint32_t bf16_rne(float f) {
  uint32_t u = __float_as_uint(f);
  return (u + 0x7fffu + ((u >> 16) & 1u)) >> 16;
}

// ---------------------------------------------------------------------------
// Pre-pass (validated r8/r9): bf16 B' frags in mfma_32x32x16 B-layout,
// symmetrized triangle. Frag fi = (c*4+kk)*4 + fh2 (1 KB): lane l holds
// B'[h = fh2*32 + (l&31)][slot = kk*16 + (l>>5)*8 + t].
// ---------------------------------------------------------------------------
__global__ void cvt_kernel(const float* __restrict__ w1f,
                           const float* __restrict__ w2f,
                           uint8_t* __restrict__ frag) {
  __shared__ float W[4096];
  __shared__ float w1c[64];
  const int tid = threadIdx.x;
  const int h = blockIdx.x;
  {
    const float* src = w2f + (size_t)h * 4096;
#pragma unroll
    for (int u = 0; u < 4; ++u)
      *(float4*)(&W[u * 1024 + tid * 4]) =
          *(const float4*)(src + u * 1024 + tid * 4);
  }
  if (tid < 64) w1c[tid] = w1f[tid * 128 + h];
  __syncthreads();
  const int fh2 = h >> 5, hl = h & 31;
  for (int idx = tid; idx < 296; idx += 256) {  // idx = c*8 + kk*2 + lh
    int c = idx >> 3, kk = (idx >> 1) & 3, lh = idx & 1;
    int a = kk * 2 + lh;
    float v[8];
    if (c < 8) {
      int ib = (c * 8 + a) * 64 + c * 8;
#pragma unroll
      for (int t = 0; t < 8; ++t) v[t] = 0.5f * W[ib + t];
    } else if (c < 36) {
      int o = c - 8, I = 0;
      while (o >= 7 - I) { o -= 7 - I; ++I; }
      int J = I + 1 + o;
      int i = I * 8 + a;
#pragma unroll
      for (int t = 0; t < 8; ++t) {
        int j = J * 8 + t;
        v[t] = 0.5f * (W[i * 64 + j] + W[j * 64 + i]);
      }
    } else {
      int sb = kk * 16 + lh * 8;
#pragma unroll
      for (int t = 0; t < 8; ++t) v[t] = w1c[sb + t];
    }
    uint4 o4;
    o4.x = (bf16_rne(v[1]) << 16) | bf16_rne(v[0]);
    o4.y = (bf16_rne(v[3]) << 16) | bf16_rne(v[2]);
    o4.z = (bf16_rne(v[5]) << 16) | bf16_rne(v[4]);
    o4.w = (bf16_rne(v[7]) << 16) | bf16_rne(v[6]);
    *(uint4*)(frag + ((size_t)((c * 4 + kk) * 4 + fh2) << 10) +
              ((lh * 32 + hl) << 4)) = o4;
  }
}

// ---------------------------------------------------------------------------
// Main: psi[m] = prod_h cos(bias[h] + sum_c A[m,·]B'[h,·]).
// Wave = 32m x 32h (mfma_f32_32x32x16_bf16); lane owns ONE x row as 32
// f32-pairs carried in doubles, made OPAQUE via asm (no remat possible), and
// amdgpu_waves_per_eu(2,2) pins the occupancy target so the wave-limiter
// cannot shrink the VGPR budget (r9/r10 lesson). 8 waves = 2 wm x 4 hq;
// grid 256; depth-2 B prefetch; zero LDS/barriers in the K-loop.
// ---------------------------------------------------------------------------
__device__ __forceinline__ uint32_t pack2(f32x2_t pr) {
  u32x2_t u = __builtin_bit_cast(u32x2_t, pr);
  return __builtin_amdgcn_perm(u[1], u[0], 0x07060302);  // hi halves (trunc)
}

__global__ void __launch_bounds__(512)
    __attribute__((amdgpu_waves_per_eu(2, 2)))
rbm_main(const float* __restrict__ xg,
         const float* __restrict__ biasg,
         const uint8_t* __restrict__ frag,
         float* __restrict__ outg) {
  __shared__ float part[4][64];
  constexpr int CI[36] = {0,1,2,3,4,5,6,7, 0,0,0,0,0,0,0, 1,1,1,1,1,1,
                          2,2,2,2,2, 3,3,3,3, 4,4,4, 5,5, 6};
  constexpr int CJ[36] = {0,1,2,3,4,5,6,7, 1,2,3,4,5,6,7, 2,3,4,5,6,7,
                          3,4,5,6,7, 4,5,6,7, 5,6,7, 6,7, 7};

  const int tid = threadIdx.x;
  const int wv = tid >> 6;
  const int wm = wv & 1;     // m half (32 rows)
  const int hq = wv >> 1;    // h quarter (32 cols)
  const int lane = tid & 63;
  const int l31 = lane & 31;
  const int lh = lane >> 5;
  const int mblk = blockIdx.x * 64;

  // lane's x row -> 32 f32-pairs in doubles; pinned opaque below
  double xb[32];
  {
    const float* p = xg + (size_t)(mblk + wm * 32 + l31) * NV;
#pragma unroll
    for (int g = 0; g < 16; ++g) {
      float4 v = *(const float4*)(p + g * 4);
      xb[g * 2]     = __builtin_bit_cast(double, f32x2_t{v.x, v.y});
      xb[g * 2 + 1] = __builtin_bit_cast(double, f32x2_t{v.z, v.w});
    }
  }
#pragma unroll
  for (int g = 0; g < 32; ++g)
    asm volatile("" : "+v"(xb[g]));   // opaque: cannot be rematerialized

  const uint8_t* pw = frag + hq * 1024 + (size_t)lane * 16;
  f32x16_t acc = (f32x16_t)0.0f;

  bf16x8_t bn[2][4];   // depth-2 prefetch ring
#pragma unroll
  for (int d = 0; d < 2; ++d)
#pragma unroll
    for (int kk = 0; kk < 4; ++kk)
      bn[d][kk] = *(const bf16x8_t*)(pw + (size_t)d * 16384 + kk * 4096);

#pragma unroll
  for (int c = 0; c < 36; ++c) {
    bf16x8_t bc[4];
#pragma unroll
    for (int kk = 0; kk < 4; ++kk) bc[kk] = bn[c & 1][kk];
    if (c + 2 <= 36) {
      const uint8_t* pn = pw + (size_t)(c + 2) * 16384;
#pragma unroll
      for (int kk = 0; kk < 4; ++kk)
        bn[c & 1][kk] = *(const bf16x8_t*)(pn + kk * 4096);
    }
    const int I = CI[c], J = CJ[c];
#pragma unroll
    for (int kk = 0; kk < 4; ++kk) {
      f32x2_t sp = __builtin_bit_cast(f32x2_t, xb[I * 4 + kk]);
      float s = lh ? sp.y : sp.x;             // v_cndmask on lane-half
      f32x2_t s2 = {s, s};
      u32x4_t adv;
#pragma unroll
      for (int tt = 0; tt < 4; ++tt) {
        f32x2_t xj = __builtin_bit_cast(f32x2_t, xb[J * 4 + tt]);
        adv[tt] = pack2(s2 * xj);             // v_pk_mul_f32 + v_perm
      }
      acc = __builtin_amdgcn_mfma_f32_32x32x16_bf16(
          __builtin_bit_cast(bf16x8_t, adv), bc[kk], acc, 0, 0, 0);
    }
  }
  // tail chunk 36 (order-1, A = x directly); lives in bn[0]
#pragma unroll
  for (int kk = 0; kk < 4; ++kk) {
    u32x4_t adv;
#pragma unroll
    for (int tt = 0; tt < 4; ++tt) {
      f32x2_t v = __builtin_bit_cast(f32x2_t, xb[kk * 8 + lh * 4 + tt]);
      adv[tt] = pack2(v);
    }
    acc = __builtin_amdgcn_mfma_f32_32x32x16_bf16(
        __builtin_bit_cast(bf16x8_t, adv), bn[0][kk], acc, 0, 0, 0);
  }

  // epilogue (r9-validated). C/D layout: col h = hq*32 + l31;
  // row m = (r&3) + 8*(r>>2) + 4*lh (+ wm*32).
  const float INV2PI = 0.15915494309189535f;
  const float bs = biasg[hq * 32 + l31];
  float pr[16];
#pragma unroll
  for (int r = 0; r < 16; ++r)
    pr[r] = __builtin_amdgcn_cosf((acc[r] + bs) * INV2PI);

#pragma unroll
  for (int ofs = 1; ofs < 32; ofs <<= 1)
#pragma unroll
    for (int r = 0; r < 16; ++r)
      pr[r] *= __shfl_xor(pr[r], ofs, 32);

  if (l31 == 0) {
#pragma unroll
    for (int r = 0; r < 16; ++r) {
      int mloc = (r & 3) + 8 * (r >> 2) + 4 * lh;
      part[hq][wm * 32 + mloc] = pr[r];
    }
  }
  __syncthreads();
  if (tid < 64) {
    float f = part[0][tid] * part[1][tid] * part[2][tid] * part[3][tid];
    outg[mblk + tid] = f;
  }
}

extern "C" void kernel_launch(void* const* d_in, const int* in_sizes, int n_in,
                              void* d_out, int out_size, void* d_ws, size_t ws_size,
                              hipStream_t stream) {
  const float* x   = (const float*)d_in[0];
  const float* w1f = (const float*)d_in[1];
  const float* w2f = (const float*)d_in[2];
  const float* hb  = (const float*)d_in[3];
  float* out = (float*)d_out;
  uint8_t* frag = (uint8_t*)d_ws;   // 592 KB bf16 frags
  (void)in_sizes; (void)n_in; (void)out_size; (void)ws_size;

  cvt_kernel<<<128, 256, 0, stream>>>(w1f, w2f, frag);
  rbm_main<<<NB / 64, 512, 0, stream>>>(x, hb, frag, out);
}

// Round 12
// 94.190 us; speedup vs baseline: 1.4649x; 1.1260x over previous
//
#include <hip/hip_runtime.h>
#include <hip/hip_bf16.h>
#include <cstdint>

#define NV 64
#define NH 128
#define NB 16384
#define PSLICE (NB * NH)   // floats per ks partial slice (8 MB)

typedef __bf16 bf16x8_t __attribute__((ext_vector_type(8)));
typedef float f32x16_t __attribute__((ext_vector_type(16)));
typedef float f32x2_t __attribute__((ext_vector_type(2)));
typedef uint32_t u32x4_t __attribute__((ext_vector_type(4)));
typedef uint32_t u32x2_t __attribute__((ext_vector_type(2)));

__device__ __forceinline__ uint32_t bf16_rne(float f) {
  uint32_t u = __float_as_uint(f);
  return (u + 0x7fffu + ((u >> 16) & 1u)) >> 16;
}

// ---------------------------------------------------------------------------
// Pre-pass (validated r8-r11, verbatim): bf16 B' frags in mfma_32x32x16
// B-layout, symmetrized triangle. Frag fi = (c*4+kk)*4 + fh2 (1 KB): lane l
// holds B'[h = fh2*32 + (l&31)][slot = kk*16 + (l>>5)*8 + t].
// ---------------------------------------------------------------------------
__global__ void cvt_kernel(const float* __restrict__ w1f,
                           const float* __restrict__ w2f,
                           uint8_t* __restrict__ frag) {
  __shared__ float W[4096];
  __shared__ float w1c[64];
  const int tid = threadIdx.x;
  const int h = blockIdx.x;
  {
    const float* src = w2f + (size_t)h * 4096;
#pragma unroll
    for (int u = 0; u < 4; ++u)
      *(float4*)(&W[u * 1024 + tid * 4]) =
          *(const float4*)(src + u * 1024 + tid * 4);
  }
  if (tid < 64) w1c[tid] = w1f[tid * 128 + h];
  __syncthreads();
  const int fh2 = h >> 5, hl = h & 31;
  for (int idx = tid; idx < 296; idx += 256) {  // idx = c*8 + kk*2 + lh
    int c = idx >> 3, kk = (idx >> 1) & 3, lh = idx & 1;
    int a = kk * 2 + lh;
    float v[8];
    if (c < 8) {
      int ib = (c * 8 + a) * 64 + c * 8;
#pragma unroll
      for (int t = 0; t < 8; ++t) v[t] = 0.5f * W[ib + t];
    } else if (c < 36) {
      int o = c - 8, I = 0;
      while (o >= 7 - I) { o -= 7 - I; ++I; }
      int J = I + 1 + o;
      int i = I * 8 + a;
#pragma unroll
      for (int t = 0; t < 8; ++t) {
        int j = J * 8 + t;
        v[t] = 0.5f * (W[i * 64 + j] + W[j * 64 + i]);
      }
    } else {
      int sb = kk * 16 + lh * 8;
#pragma unroll
      for (int t = 0; t < 8; ++t) v[t] = w1c[sb + t];
    }
    uint4 o4;
    o4.x = (bf16_rne(v[1]) << 16) | bf16_rne(v[0]);
    o4.y = (bf16_rne(v[3]) << 16) | bf16_rne(v[2]);
    o4.z = (bf16_rne(v[5]) << 16) | bf16_rne(v[4]);
    o4.w = (bf16_rne(v[7]) << 16) | bf16_rne(v[6]);
    *(uint4*)(frag + ((size_t)((c * 4 + kk) * 4 + fh2) << 10) +
              ((lh * 32 + hl) << 4)) = o4;
  }
}

// ---------------------------------------------------------------------------
// Main: P[ks][m][h] partials. Wave = 64m x 64h (2 im x 2 ih tiles of
// mfma_f32_32x32x16_bf16): each B-frag feeds 2 MFMAs -> B VMEM traffic
// halves (the dominant pipe). x lives in LDS as bf16 rows (stride 144 B:
// ds_read_b128 conflict-free, lane-halves broadcast) -- NO per-lane x array
// to spill/remat/promote (r6-r11 lesson). Block 256 thr = 2 wm x 2 hh waves
// = 128m x 128h; grid (128, 4 ks) -> 2 blocks/CU, 2 waves/SIMD (pinned).
// ---------------------------------------------------------------------------
__device__ __forceinline__ uint32_t pack2(f32x2_t pr) {
  u32x2_t u = __builtin_bit_cast(u32x2_t, pr);
  return __builtin_amdgcn_perm(u[1], u[0], 0x07060302);  // hi halves (trunc)
}

template <int C0, int C1, bool TAIL>
__device__ __forceinline__ void kloop(const uint8_t* pb,
                                      const uint16_t* xr0,
                                      const uint16_t* xr1,
                                      int lh, f32x16_t acc[2][2]) {
  constexpr int CI[36] = {0,1,2,3,4,5,6,7, 0,0,0,0,0,0,0, 1,1,1,1,1,1,
                          2,2,2,2,2, 3,3,3,3, 4,4,4, 5,5, 6};
  constexpr int CJ[36] = {0,1,2,3,4,5,6,7, 1,2,3,4,5,6,7, 2,3,4,5,6,7,
                          3,4,5,6,7, 4,5,6,7, 5,6,7, 6,7, 7};
  bf16x8_t bn[8];  // prefetch ring: idx = kk*2 + ih
#pragma unroll
  for (int kk = 0; kk < 4; ++kk)
#pragma unroll
    for (int ih = 0; ih < 2; ++ih)
      bn[kk * 2 + ih] =
          *(const bf16x8_t*)(pb + (size_t)C0 * 16384 + kk * 4096 + ih * 1024);

#pragma unroll
  for (int c = C0; c < C1; ++c) {
    bf16x8_t bc[8];
#pragma unroll
    for (int u = 0; u < 8; ++u) bc[u] = bn[u];
    if (c + 1 < (TAIL ? 37 : C1)) {
      const uint8_t* pn = pb + (size_t)(c + 1) * 16384;
#pragma unroll
      for (int kk = 0; kk < 4; ++kk)
#pragma unroll
        for (int ih = 0; ih < 2; ++ih)
          bn[kk * 2 + ih] = *(const bf16x8_t*)(pn + kk * 4096 + ih * 1024);
    }
    const int I = CI[c], J = CJ[c];
    u32x4_t xi[2], xj[2];
    xi[0] = *(const u32x4_t*)(xr0 + I * 8);
    xj[0] = *(const u32x4_t*)(xr0 + J * 8);
    xi[1] = *(const u32x4_t*)(xr1 + I * 8);
    xj[1] = *(const u32x4_t*)(xr1 + J * 8);
    f32x2_t xjf[2][4];
#pragma unroll
    for (int im = 0; im < 2; ++im)
#pragma unroll
      for (int w = 0; w < 4; ++w)
        xjf[im][w] = f32x2_t{__uint_as_float(xj[im][w] << 16),
                             __uint_as_float(xj[im][w] & 0xffff0000u)};
#pragma unroll
    for (int kk = 0; kk < 4; ++kk) {
      bf16x8_t af[2];
#pragma unroll
      for (int im = 0; im < 2; ++im) {
        uint32_t su = xi[im][kk];
        uint32_t sel = lh ? (su & 0xffff0000u) : (su << 16);
        float s = __uint_as_float(sel);
        f32x2_t s2 = {s, s};
        u32x4_t adv;
#pragma unroll
        for (int tt = 0; tt < 4; ++tt)
          adv[tt] = pack2(s2 * xjf[im][tt]);  // v_pk_mul_f32 + v_perm
        af[im] = __builtin_bit_cast(bf16x8_t, adv);
      }
#pragma unroll
      for (int ih = 0; ih < 2; ++ih)
#pragma unroll
        for (int im = 0; im < 2; ++im)
          acc[im][ih] = __builtin_amdgcn_mfma_f32_32x32x16_bf16(
              af[im], bc[kk * 2 + ih], acc[im][ih], 0, 0, 0);
    }
  }
  if (TAIL) {  // chunk 36 (order-1): A = x directly; bn holds its frags
#pragma unroll
    for (int kk = 0; kk < 4; ++kk) {
      bf16x8_t af[2];
      af[0] = __builtin_bit_cast(
          bf16x8_t, *(const u32x4_t*)(xr0 + (kk * 2 + lh) * 8));
      af[1] = __builtin_bit_cast(
          bf16x8_t, *(const u32x4_t*)(xr1 + (kk * 2 + lh) * 8));
#pragma unroll
      for (int ih = 0; ih < 2; ++ih)
#pragma unroll
        for (int im = 0; im < 2; ++im)
          acc[im][ih] = __builtin_amdgcn_mfma_f32_32x32x16_bf16(
              af[im], bn[kk * 2 + ih], acc[im][ih], 0, 0, 0);
    }
  }
}

__global__ void __launch_bounds__(256)
    __attribute__((amdgpu_waves_per_eu(2, 2)))
rbm_main(const float* __restrict__ xg,
         const uint8_t* __restrict__ frag,
         float* __restrict__ P) {
  __shared__ __align__(16) uint16_t xt[128 * 72];  // bf16 rows, stride 144 B

  const int tid = threadIdx.x;
  const int wv = tid >> 6;
  const int wm = wv & 1;     // m half (64 rows)
  const int hh = wv >> 1;    // h half (64 cols)
  const int lane = tid & 63;
  const int l31 = lane & 31;
  const int lh = lane >> 5;
  const int mblk = blockIdx.x * 128;
  const int ks = blockIdx.y;

  // stage x: thread pair covers one row (coalesced 256 B/row)
  {
    int row = tid >> 1, half = tid & 1;
    const float* p = xg + (size_t)(mblk + row) * NV + half * 32;
    uint16_t* d = &xt[row * 72 + half * 32];
#pragma unroll
    for (int g = 0; g < 8; ++g) {
      float4 v = *(const float4*)(p + g * 4);
      *(uint32_t*)(d + g * 4)     = (bf16_rne(v.y) << 16) | bf16_rne(v.x);
      *(uint32_t*)(d + g * 4 + 2) = (bf16_rne(v.w) << 16) | bf16_rne(v.z);
    }
  }
  __syncthreads();

  const uint16_t* xr0 = &xt[(wm * 64 + l31) * 72];
  const uint16_t* xr1 = xr0 + 32 * 72;
  const uint8_t* pb = frag + (size_t)(hh * 2) * 1024 + (size_t)lane * 16;

  f32x16_t acc[2][2] = {{(f32x16_t)0.0f, (f32x16_t)0.0f},
                        {(f32x16_t)0.0f, (f32x16_t)0.0f}};

  if (ks == 0)      kloop<0, 9, false>(pb, xr0, xr1, lh, acc);
  else if (ks == 1) kloop<9, 18, false>(pb, xr0, xr1, lh, acc);
  else if (ks == 2) kloop<18, 27, false>(pb, xr0, xr1, lh, acc);
  else              kloop<27, 36, true>(pb, xr0, xr1, lh, acc);

  // store partials. C/D layout (r8-validated): col h = hh*64 + ih*32 + l31;
  // row m = mblk + wm*64 + im*32 + (r&3) + 8*(r>>2) + 4*lh.
  float* pp = P + (size_t)ks * PSLICE +
              (size_t)(mblk + wm * 64) * NH + hh * 64 + l31;
#pragma unroll
  for (int im = 0; im < 2; ++im)
#pragma unroll
    for (int ih = 0; ih < 2; ++ih)
#pragma unroll
      for (int r = 0; r < 16; ++r) {
        int mloc = im * 32 + (r & 3) + 8 * (r >> 2) + 4 * lh;
        pp[(size_t)mloc * NH + ih * 32] = acc[im][ih][r];
      }
}

// ---------------------------------------------------------------------------
// Reduce (r9-validated pattern, 4 slices): psi[m] = prod_h cos(sum P + bias).
// ---------------------------------------------------------------------------
__global__ void reduce_kernel(const float* __restrict__ P,
                              const float* __restrict__ biasg,
                              float* __restrict__ outg) {
  const int tid = threadIdx.x;
  const int wv = tid >> 6;
  const int lane = tid & 63;
  const int m0 = blockIdx.x * 32 + wv * 8;
  const float2 b2 = *(const float2*)(biasg + 2 * lane);
  const float INV2PI = 0.15915494309189535f;
#pragma unroll
  for (int u = 0; u < 8; ++u) {
    const int m = m0 + u;
    const float* pm = P + (size_t)m * NH + 2 * lane;
    float ax = b2.x, ay = b2.y;
#pragma unroll
    for (int s = 0; s < 4; ++s) {
      float2 a = *(const float2*)(pm + (size_t)s * PSLICE);
      ax += a.x; ay += a.y;
    }
    float pr = __builtin_amdgcn_cosf(ax * INV2PI) *
               __builtin_amdgcn_cosf(ay * INV2PI);
#pragma unroll
    for (int ofs = 1; ofs < 64; ofs <<= 1)
      pr *= __shfl_xor(pr, ofs, 64);
    if (lane == 0) outg[m] = pr;
  }
}

extern "C" void kernel_launch(void* const* d_in, const int* in_sizes, int n_in,
                              void* d_out, int out_size, void* d_ws, size_t ws_size,
                              hipStream_t stream) {
  const float* x   = (const float*)d_in[0];
  const float* w1f = (const float*)d_in[1];
  const float* w2f = (const float*)d_in[2];
  const float* hb  = (const float*)d_in[3];
  float* out = (float*)d_out;
  uint8_t* frag = (uint8_t*)d_ws;                    // 592 KB bf16 frags
  float* P = (float*)((uint8_t*)d_ws + (1 << 20));   // 4 x 8 MB partials
  (void)in_sizes; (void)n_in; (void)out_size; (void)ws_size;

  cvt_kernel<<<128, 256, 0, stream>>>(w1f, w2f, frag);
  rbm_main<<<dim3(NB / 128, 4), 256, 0, stream>>>(x, frag, P);
  reduce_kernel<<<NB / 32, 256, 0, stream>>>(P, hb, out);
}